// Round 8
// baseline (239.969 us; speedup 1.0000x reference)
//
#include <hip/hip_runtime.h>
#include <hip/hip_bf16.h>

typedef __attribute__((ext_vector_type(8))) short bf16x8;
typedef __attribute__((ext_vector_type(4))) short bf16x4;
typedef __attribute__((ext_vector_type(4))) float f32x4;

static __device__ __forceinline__ __hip_bfloat16 f2b(float f) {
    return __float2bfloat16(f);
}
static __device__ __forceinline__ unsigned pack2(float a, float b) {
    unsigned ua = (unsigned)__bfloat16_as_ushort(__float2bfloat16(a));
    unsigned ub = (unsigned)__bfloat16_as_ushort(__float2bfloat16(b));
    return ua | (ub << 16);
}
static __device__ __forceinline__ float exp2fast(float x) {
    return __builtin_amdgcn_exp2f(x);
}

// ---------------------------------------------------------------------------
// f32 -> bf16 elementwise convert
// ---------------------------------------------------------------------------
__global__ __launch_bounds__(256) void k_f32_to_bf16(
    const float* __restrict__ in, __hip_bfloat16* __restrict__ out, int n4)
{
    int i = blockIdx.x * blockDim.x + threadIdx.x;
    int stride = gridDim.x * blockDim.x;
    for (; i < n4; i += stride) {
        float4 v = reinterpret_cast<const float4*>(in)[i];
        __hip_bfloat16* o = out + 4 * (size_t)i;
        o[0] = f2b(v.x); o[1] = f2b(v.y); o[2] = f2b(v.z); o[3] = f2b(v.w);
    }
}

// ---------------------------------------------------------------------------
// f32 [R][Cn] -> bf16 [Cn][R] tiled transpose
// ---------------------------------------------------------------------------
__global__ __launch_bounds__(256) void k_transpose_f32_bf16(
    const float* __restrict__ in, __hip_bfloat16* __restrict__ out, int R, int Cn)
{
    __shared__ float tile[32][33];
    const int c0 = blockIdx.x * 32, r0 = blockIdx.y * 32;
    const int tx = threadIdx.x & 31, ty = threadIdx.x >> 5;
#pragma unroll
    for (int i = 0; i < 32; i += 8)
        tile[ty + i][tx] = in[(size_t)(r0 + ty + i) * Cn + c0 + tx];
    __syncthreads();
#pragma unroll
    for (int i = 0; i < 32; i += 8)
        out[(size_t)(c0 + ty + i) * R + r0 + tx] = f2b(tile[tx][ty + i]);
}

#define QSCALE 0.1803368801111f   // 0.125 * log2(e)

// ---------------------------------------------------------------------------
// GEMM1 qkv: 128x128 tile, BK=32, 2-phase dbuf LDS (32 KB -> 3 blocks/CU),
// both-sides swizzle (source pre-swizzle chunk^=(row>>1)&3, swizzled ds_read)
// -> 2-way bank conflicts. 768 blocks = exactly 3/CU co-resident.
// ---------------------------------------------------------------------------
#define QK_STAGE(buf, kt)                                                       \
    {                                                                           \
        const int k0_ = (kt) << 5;                                              \
        _Pragma("unroll")                                                       \
        for (int i = 0; i < 2; ++i) {                                           \
            const int idx = i * 256 + tid;                                      \
            const int r_ = idx >> 2;                                            \
            const int j_ = idx & 3;                                             \
            const int js_ = j_ ^ ((r_ >> 1) & 3);                               \
            __builtin_amdgcn_global_load_lds(                                   \
                (const __attribute__((address_space(1))) void*)(A + (size_t)(m0 + r_) * K + k0_ + js_ * 8), \
                (__attribute__((address_space(3))) void*)(&As[buf][r_][j_ * 8]), 16, 0, 0); \
        }                                                                       \
        _Pragma("unroll")                                                       \
        for (int i = 0; i < 2; ++i) {                                           \
            const int idx = i * 256 + tid;                                      \
            const int r_ = idx >> 2;                                            \
            const int j_ = idx & 3;                                             \
            const int js_ = j_ ^ ((r_ >> 1) & 3);                               \
            __builtin_amdgcn_global_load_lds(                                   \
                (const __attribute__((address_space(1))) void*)(Bt + (size_t)(n0 + r_) * K + k0_ + js_ * 8), \
                (__attribute__((address_space(3))) void*)(&Bs[buf][r_][j_ * 8]), 16, 0, 0); \
        }                                                                       \
    }

__global__ __launch_bounds__(256, 3) void k_gemm_qkv(
    const __hip_bfloat16* __restrict__ A,
    const __hip_bfloat16* __restrict__ Bt,
    const float* __restrict__ bias,
    int K,
    __hip_bfloat16* __restrict__ Qb,
    __hip_bfloat16* __restrict__ Kb,
    __hip_bfloat16* __restrict__ Vt)
{
    __shared__ __hip_bfloat16 As[2][128][32];
    __shared__ __hip_bfloat16 Bs[2][128][32];

    const int tid = threadIdx.x;
    const int lane = tid & 63;
    const int wid = tid >> 6;
    const int wm = wid >> 1, wn = wid & 1;
    const int m0 = blockIdx.y * 128, n0 = blockIdx.x * 128;
    const int l15 = lane & 15, lg = lane >> 4;
    const int rchunk = (lg ^ ((l15 >> 1) & 3)) * 8;   // swizzled read chunk

    f32x4 acc[4][4] = {};
    const int nt = K >> 5;   // 32

    QK_STAGE(0, 0);
    __syncthreads();
    int cur = 0;
    for (int t = 0; t < nt; ++t) {
        if (t + 1 < nt) QK_STAGE(cur ^ 1, t + 1);
        bf16x8 a[4], bb[4];
#pragma unroll
        for (int m = 0; m < 4; ++m)
            a[m] = *(const bf16x8*)&As[cur][wm * 64 + m * 16 + l15][rchunk];
#pragma unroll
        for (int n = 0; n < 4; ++n)
            bb[n] = *(const bf16x8*)&Bs[cur][wn * 64 + n * 16 + l15][rchunk];
        __builtin_amdgcn_s_setprio(1);
#pragma unroll
        for (int m = 0; m < 4; ++m)
#pragma unroll
            for (int n = 0; n < 4; ++n)
                acc[m][n] = __builtin_amdgcn_mfma_f32_16x16x32_bf16(a[m], bb[n], acc[m][n], 0, 0, 0);
        __builtin_amdgcn_s_setprio(0);
        __syncthreads();
        cur ^= 1;
    }

#pragma unroll
    for (int m = 0; m < 4; ++m) {
        const int row = m0 + wm * 64 + m * 16 + lg * 4;
#pragma unroll
        for (int n = 0; n < 4; ++n) {
            const int col = n0 + wn * 64 + n * 16 + l15;
            const float bv = bias[col];
#pragma unroll
            for (int r = 0; r < 4; ++r) {
                const float val = acc[m][n][r] + bv;
                const int rr = row + r;
                const int sec = col >> 10, cw = col & 1023;
                const int hh = cw >> 6, d = cw & 63;
                const int bq = rr >> 11, tt = rr & 2047;
                const int bh = bq * 16 + hh;
                if (sec == 0)
                    Qb[((size_t)bh * 2048 + tt) * 64 + d] = f2b(val * QSCALE);
                else if (sec == 1)
                    Kb[((size_t)bh * 2048 + tt) * 64 + d] = f2b(val);
                else
                    Vt[((size_t)bh * 64 + d) * 2048 + tt] = f2b(val);
            }
        }
    }
}

// ---------------------------------------------------------------------------
// GEMM out: 128x64 tile, BK=32, dbuf (24 KB LDS), 512 blocks (2+/CU).
// ---------------------------------------------------------------------------
#define OUT_STAGE(buf, kt)                                                      \
    {                                                                           \
        const int k0_ = (kt) << 5;                                              \
        _Pragma("unroll")                                                       \
        for (int i = 0; i < 2; ++i) {                                           \
            const int idx = i * 256 + tid;                                      \
            const int r_ = idx >> 2;                                            \
            const int j_ = idx & 3;                                             \
            const int js_ = j_ ^ ((r_ >> 1) & 3);                               \
            __builtin_amdgcn_global_load_lds(                                   \
                (const __attribute__((address_space(1))) void*)(A + (size_t)(m0 + r_) * K + k0_ + js_ * 8), \
                (__attribute__((address_space(3))) void*)(&As[buf][r_][j_ * 8]), 16, 0, 0); \
        }                                                                       \
        {                                                                       \
            const int r_ = tid >> 2;                                            \
            const int j_ = tid & 3;                                             \
            const int js_ = j_ ^ ((r_ >> 1) & 3);                               \
            __builtin_amdgcn_global_load_lds(                                   \
                (const __attribute__((address_space(1))) void*)(Bt + (size_t)(n0 + r_) * K + k0_ + js_ * 8), \
                (__attribute__((address_space(3))) void*)(&Bs[buf][r_][j_ * 8]), 16, 0, 0); \
        }                                                                       \
    }

__global__ __launch_bounds__(256, 4) void k_gemm_out(
    const __hip_bfloat16* __restrict__ A,
    const __hip_bfloat16* __restrict__ Bt,
    const float* __restrict__ bias,
    int K, int Nn,
    float* __restrict__ outf)
{
    __shared__ __hip_bfloat16 As[2][128][32];
    __shared__ __hip_bfloat16 Bs[2][64][32];

    const int tid = threadIdx.x;
    const int lane = tid & 63;
    const int wid = tid >> 6;
    const int wm = wid >> 1, wn = wid & 1;        // wave: 64 rows x 32 cols
    const int m0 = blockIdx.y * 128, n0 = blockIdx.x * 64;
    const int l15 = lane & 15, lg = lane >> 4;
    const int rchunk = (lg ^ ((l15 >> 1) & 3)) * 8;

    f32x4 acc[4][2] = {};
    const int nt = K >> 5;

    OUT_STAGE(0, 0);
    __syncthreads();
    int cur = 0;
    for (int t = 0; t < nt; ++t) {
        if (t + 1 < nt) OUT_STAGE(cur ^ 1, t + 1);
        bf16x8 a[4], bb[2];
#pragma unroll
        for (int m = 0; m < 4; ++m)
            a[m] = *(const bf16x8*)&As[cur][wm * 64 + m * 16 + l15][rchunk];
#pragma unroll
        for (int n = 0; n < 2; ++n)
            bb[n] = *(const bf16x8*)&Bs[cur][wn * 32 + n * 16 + l15][rchunk];
        __builtin_amdgcn_s_setprio(1);
#pragma unroll
        for (int m = 0; m < 4; ++m)
#pragma unroll
            for (int n = 0; n < 2; ++n)
                acc[m][n] = __builtin_amdgcn_mfma_f32_16x16x32_bf16(a[m], bb[n], acc[m][n], 0, 0, 0);
        __builtin_amdgcn_s_setprio(0);
        __syncthreads();
        cur ^= 1;
    }

#pragma unroll
    for (int m = 0; m < 4; ++m) {
        const int row = m0 + wm * 64 + m * 16 + lg * 4;
#pragma unroll
        for (int n = 0; n < 2; ++n) {
            const int col = n0 + wn * 32 + n * 16 + l15;
            const float bv = bias[col];
#pragma unroll
            for (int r = 0; r < 4; ++r)
                outf[(size_t)(row + r) * Nn + col] = acc[m][n][r] + bv;
        }
    }
}

// ---------------------------------------------------------------------------
// Causal flash attention v6 — 16 q-rows/wave, 1024 blocks x 4 waves
// (4096 waves -> up to 4 waves/SIMD), v5 machinery otherwise.
// ---------------------------------------------------------------------------
#define DEFER_THR 4.0f

#define K_LOAD16(BK_, KS)                                                       \
    {                                                                           \
        _Pragma("unroll")                                                       \
        for (int kf = 0; kf < 4; ++kf) {                                        \
            const __hip_bfloat16* kp =                                          \
                Kbase + (size_t)((KS) + kf * 16 + l15) * 64 + lg * 8;           \
            BK_[kf][0] = *(const bf16x8*)(kp);                                  \
            BK_[kf][1] = *(const bf16x8*)(kp + 32);                             \
        }                                                                       \
    }

#define FULL16(BK_, BKN_, KS)                                                   \
    {                                                                           \
        const int ks_ = (KS);                                                   \
        bf16x8 bv[4][2];                                                        \
        _Pragma("unroll")                                                       \
        for (int dc = 0; dc < 4; ++dc) {                                        \
            const __hip_bfloat16* vp =                                          \
                Vbase + (size_t)(dc * 16 + l15) * 2048 + ks_ + lg * 8;          \
            bv[dc][0] = *(const bf16x8*)(vp);                                   \
            bv[dc][1] = *(const bf16x8*)(vp + 32);                              \
        }                                                                       \
        K_LOAD16(BKN_, ks_ + 64);                                               \
        f32x4 s[4] = {};                                                        \
        __builtin_amdgcn_s_setprio(1);                                          \
        _Pragma("unroll")                                                       \
        for (int kf = 0; kf < 4; ++kf) {                                        \
            s[kf] = __builtin_amdgcn_mfma_f32_16x16x32_bf16(BK_[kf][0], aq0, s[kf], 0, 0, 0); \
            s[kf] = __builtin_amdgcn_mfma_f32_16x16x32_bf16(BK_[kf][1], aq1, s[kf], 0, 0, 0); \
        }                                                                       \
        __builtin_amdgcn_s_setprio(0);                                          \
        float px = fmaxf(fmaxf(fmaxf(s[0][0], s[0][1]), fmaxf(s[0][2], s[0][3])), \
                         fmaxf(fmaxf(s[1][0], s[1][1]), fmaxf(s[1][2], s[1][3]))); \
        px = fmaxf(px, fmaxf(fmaxf(fmaxf(s[2][0], s[2][1]), fmaxf(s[2][2], s[2][3])), \
                             fmaxf(fmaxf(s[3][0], s[3][1]), fmaxf(s[3][2], s[3][3])))); \
        px = fmaxf(px, __shfl_xor(px, 16));                                     \
        px = fmaxf(px, __shfl_xor(px, 32));                                     \
        if (__any(px > mr_ + DEFER_THR)) {                                      \
            const float mn_ = fmaxf(mr_, px);                                   \
            const float al_ = exp2fast(mr_ - mn_);                              \
            mr_ = mn_; lr_ *= al_;                                              \
            _Pragma("unroll")                                                   \
            for (int dc = 0; dc < 4; ++dc)                                      \
                _Pragma("unroll")                                               \
                for (int r = 0; r < 4; ++r) o[dc][r] *= al_;                    \
        }                                                                       \
        float rs_ = 0.f;                                                        \
        _Pragma("unroll")                                                       \
        for (int kf = 0; kf < 4; ++kf) {                                        \
            _Pragma("unroll")                                                   \
            for (int r = 0; r < 4; ++r) {                                       \
                s[kf][r] = exp2fast(s[kf][r] - mr_);                            \
                rs_ += s[kf][r];                                                \
            }                                                                   \
            uint2 w_;                                                           \
            w_.x = pack2(s[kf][0], s[kf][1]);                                   \
            w_.y = pack2(s[kf][2], s[kf][3]);                                   \
            *(uint2*)&Pw[l15 * 64 + ((kf * 16 + lg * 4) ^ swz)] = w_;           \
        }                                                                       \
        rs_ += __shfl_xor(rs_, 16);                                             \
        rs_ += __shfl_xor(rs_, 32);                                             \
        lr_ += rs_;                                                             \
        _Pragma("unroll")                                                       \
        for (int c2 = 0; c2 < 2; ++c2) {                                        \
            const bf16x8 pb = *(const bf16x8*)&Pw[l15 * 64 + ((c2 * 32 + lg * 8) ^ swz)]; \
            __builtin_amdgcn_s_setprio(1);                                      \
            _Pragma("unroll")                                                   \
            for (int dc = 0; dc < 4; ++dc)                                      \
                o[dc] = __builtin_amdgcn_mfma_f32_16x16x32_bf16(bv[dc][c2], pb, o[dc], 0, 0, 0); \
            __builtin_amdgcn_s_setprio(0);                                      \
        }                                                                       \
    }

#define TAIL16(BK_)                                                             \
    {                                                                           \
        const int ks_ = nfull * 64;                                             \
        bf16x8 bv[4][2];                                                        \
        _Pragma("unroll")                                                       \
        for (int dc = 0; dc < 4; ++dc) {                                        \
            const __hip_bfloat16* vp =                                          \
                Vbase + (size_t)(dc * 16 + l15) * 2048 + ks_ + lg * 8;          \
            bv[dc][0] = *(const bf16x8*)(vp);                                   \
            bv[dc][1] = *(const bf16x8*)(vp + 32);                              \
        }                                                                       \
        const int qv = qw + l15;                                                \
        f32x4 s[4] = {};                                                        \
        _Pragma("unroll")                                                       \
        for (int kf = 0; kf < 4; ++kf) {                                        \
            if (ks_ + kf * 16 <= qw + 15) {                                     \
                s[kf] = __builtin_amdgcn_mfma_f32_16x16x32_bf16(BK_[kf][0], aq0, s[kf], 0, 0, 0); \
                s[kf] = __builtin_amdgcn_mfma_f32_16x16x32_bf16(BK_[kf][1], aq1, s[kf], 0, 0, 0); \
            }                                                                   \
        }                                                                       \
        float p[4][4];                                                          \
        const int kb = ks_ + lg * 4;                                            \
        _Pragma("unroll")                                                       \
        for (int kf = 0; kf < 4; ++kf)                                          \
            _Pragma("unroll")                                                   \
            for (int r = 0; r < 4; ++r)                                         \
                p[kf][r] = (kb + kf * 16 + r <= qv) ? s[kf][r] : -1e30f;        \
        float mx = fmaxf(fmaxf(fmaxf(p[0][0], p[0][1]), fmaxf(p[0][2], p[0][3])), \
                         fmaxf(fmaxf(p[1][0], p[1][1]), fmaxf(p[1][2], p[1][3]))); \
        mx = fmaxf(mx, fmaxf(fmaxf(fmaxf(p[2][0], p[2][1]), fmaxf(p[2][2], p[2][3])), \
                             fmaxf(fmaxf(p[3][0], p[3][1]), fmaxf(p[3][2], p[3][3])))); \
        mx = fmaxf(mx, __shfl_xor(mx, 16));                                     \
        mx = fmaxf(mx, __shfl_xor(mx, 32));                                     \
        const float mnew = fmaxf(mr_, mx);                                      \
        const float al_ = exp2fast(mr_ - mnew);                                 \
        mr_ = mnew;                                                             \
        float rs_ = 0.f;                                                        \
        _Pragma("unroll")                                                       \
        for (int kf = 0; kf < 4; ++kf)                                          \
            _Pragma("unroll")                                                   \
            for (int r = 0; r < 4; ++r) {                                       \
                p[kf][r] = exp2fast(p[kf][r] - mnew);                           \
                rs_ += p[kf][r];                                                \
            }                                                                   \
        rs_ += __shfl_xor(rs_, 16);                                             \
        rs_ += __shfl_xor(rs_, 32);                                             \
        lr_ = lr_ * al_ + rs_;                                                  \
        _Pragma("unroll")                                                       \
        for (int dc = 0; dc < 4; ++dc)                                          \
            _Pragma("unroll")                                                   \
            for (int r = 0; r < 4; ++r) o[dc][r] *= al_;                        \
        _Pragma("unroll")                                                       \
        for (int kf = 0; kf < 4; ++kf) {                                        \
            uint2 w_;                                                           \
            w_.x = pack2(p[kf][0], p[kf][1]);                                   \
            w_.y = pack2(p[kf][2], p[kf][3]);                                   \
            *(uint2*)&Pw[l15 * 64 + ((kf * 16 + lg * 4) ^ swz)] = w_;           \
        }                                                                       \
        _Pragma("unroll")                                                       \
        for (int c2 = 0; c2 < 2; ++c2) {                                        \
            if (ks_ + c2 * 32 <= qw + 15) {                                     \
                const bf16x8 pb = *(const bf16x8*)&Pw[l15 * 64 + ((c2 * 32 + lg * 8) ^ swz)]; \
                _Pragma("unroll")                                               \
                for (int dc = 0; dc < 4; ++dc)                                  \
                    o[dc] = __builtin_amdgcn_mfma_f32_16x16x32_bf16(bv[dc][c2], pb, o[dc], 0, 0, 0); \
            }                                                                   \
        }                                                                       \
    }

__global__ __launch_bounds__(256, 4) void k_attn(
    const __hip_bfloat16* __restrict__ Qb,
    const __hip_bfloat16* __restrict__ Kb,
    const __hip_bfloat16* __restrict__ Vt,
    __hip_bfloat16* __restrict__ att)
{
    __shared__ __hip_bfloat16 P_lds[4][16 * 64];
    const int tid = threadIdx.x, lane = tid & 63, wid = tid >> 6;
    const int lid = blockIdx.x;
    const int xcd = lid & 7, j = lid >> 3;       // j 0..127
    const int bh = xcd * 4 + (j & 3);            // 4 heads per XCD
    const int tt = j >> 2;                       // 0..31
    const int tile = (tt < 16) ? (31 - tt) : (tt - 16);   // heavy first
    const int q0 = tile * 64;
    const int qw = q0 + wid * 16;
    const int l15 = lane & 15, lg = lane >> 4;
    const int swz = (l15 & 7) << 3;

    const __hip_bfloat16* Qbase = Qb + (size_t)bh * 2048 * 64;
    const __hip_bfloat16* Kbase = Kb + (size_t)bh * 2048 * 64;
    const __hip_bfloat16* Vbase = Vt + (size_t)bh * 64 * 2048;

    const bf16x8 aq0 = *(const bf16x8*)(Qbase + (size_t)(qw + l15) * 64 + lg * 8);
    const bf16x8 aq1 = *(const bf16x8*)(Qbase + (size_t)(qw + l15) * 64 + 32 + lg * 8);

    f32x4 o[4] = {};
    float mr_ = -1e30f, lr_ = 0.f;

    const int nfull = qw >> 6;
    __hip_bfloat16* Pw = &P_lds[wid][0];

    bf16x8 bkA[4][2], bkB[4][2];
    K_LOAD16(bkA, 0);

    if (nfull & 1) {
        FULL16(bkA, bkB, 0);
        for (int t = 1; t < nfull; t += 2) {
            FULL16(bkB, bkA, t * 64);
            FULL16(bkA, bkB, (t + 1) * 64);
        }
        TAIL16(bkB);
    } else {
        for (int t = 0; t < nfull; t += 2) {
            FULL16(bkA, bkB, t * 64);
            FULL16(bkB, bkA, (t + 1) * 64);
        }
        TAIL16(bkA);
    }

    const int bq = bh >> 4, hh = bh & 15;
    const float inv = 1.0f / lr_;
    const size_t rowb = ((size_t)(bq * 2048 + qw + l15)) * 1024 + hh * 64;
#pragma unroll
    for (int dc = 0; dc < 4; ++dc) {
        bf16x4 st;
#pragma unroll
        for (int r = 0; r < 4; ++r)
            st[r] = (short)__bfloat16_as_ushort(__float2bfloat16(o[dc][r] * inv));
        *(bf16x4*)(att + rowb + dc * 16 + lg * 4) = st;
    }
}

// ---------------------------------------------------------------------------
extern "C" void kernel_launch(void* const* d_in, const int* in_sizes, int n_in,
                              void* d_out, int out_size, void* d_ws, size_t ws_size,
                              hipStream_t stream)
{
    const float* x    = (const float*)d_in[0];   // [2,2048,1024]
    const float* Wqkv = (const float*)d_in[1];   // [1024,3072]
    const float* bqkv = (const float*)d_in[2];   // [3072]
    const float* Wo   = (const float*)d_in[3];   // [1024,1024]
    const float* bo   = (const float*)d_in[4];   // [1024]
    float* out = (float*)d_out;                  // [2,2048,1024]

    char* ws = (char*)d_ws;
    const size_t MB = 1024 * 1024;
    __hip_bfloat16* xb    = (__hip_bfloat16*)(ws);            //  8 MB
    __hip_bfloat16* WqkvT = (__hip_bfloat16*)(ws + 8 * MB);   //  6 MB
    __hip_bfloat16* WoT   = (__hip_bfloat16*)(ws + 14 * MB);  //  2 MB
    __hip_bfloat16* Qb    = (__hip_bfloat16*)(ws + 16 * MB);  //  8 MB
    __hip_bfloat16* Kb    = (__hip_bfloat16*)(ws + 24 * MB);  //  8 MB
    __hip_bfloat16* Vt    = (__hip_bfloat16*)(ws + 32 * MB);  //  8 MB
    __hip_bfloat16* att   = (__hip_bfloat16*)(ws + 40 * MB);  //  8 MB

    k_f32_to_bf16<<<2048, 256, 0, stream>>>(x, xb, 4096 * 1024 / 4);
    k_transpose_f32_bf16<<<dim3(96, 32), 256, 0, stream>>>(Wqkv, WqkvT, 1024, 3072);
    k_transpose_f32_bf16<<<dim3(32, 32), 256, 0, stream>>>(Wo, WoT, 1024, 1024);

    k_gemm_qkv<<<dim3(24, 32), 256, 0, stream>>>(
        xb, WqkvT, bqkv, 1024, Qb, Kb, Vt);

    k_attn<<<1024, 256, 0, stream>>>(Qb, Kb, Vt, att);

    k_gemm_out<<<dim3(16, 32), 256, 0, stream>>>(
        att, WoT, bo, 1024, 1024, out);
}

// Round 9
// 194.920 us; speedup vs baseline: 1.2311x; 1.2311x over previous
//
#include <hip/hip_runtime.h>
#include <hip/hip_bf16.h>

typedef __attribute__((ext_vector_type(8))) short bf16x8;
typedef __attribute__((ext_vector_type(4))) short bf16x4;
typedef __attribute__((ext_vector_type(4))) float f32x4;

static __device__ __forceinline__ __hip_bfloat16 f2b(float f) {
    return __float2bfloat16(f);
}
static __device__ __forceinline__ unsigned pack2(float a, float b) {
    unsigned ua = (unsigned)__bfloat16_as_ushort(__float2bfloat16(a));
    unsigned ub = (unsigned)__bfloat16_as_ushort(__float2bfloat16(b));
    return ua | (ub << 16);
}
static __device__ __forceinline__ float exp2fast(float x) {
    return __builtin_amdgcn_exp2f(x);
}

// ---------------------------------------------------------------------------
// f32 -> bf16 elementwise convert
// ---------------------------------------------------------------------------
__global__ __launch_bounds__(256) void k_f32_to_bf16(
    const float* __restrict__ in, __hip_bfloat16* __restrict__ out, int n4)
{
    int i = blockIdx.x * blockDim.x + threadIdx.x;
    int stride = gridDim.x * blockDim.x;
    for (; i < n4; i += stride) {
        float4 v = reinterpret_cast<const float4*>(in)[i];
        __hip_bfloat16* o = out + 4 * (size_t)i;
        o[0] = f2b(v.x); o[1] = f2b(v.y); o[2] = f2b(v.z); o[3] = f2b(v.w);
    }
}

// ---------------------------------------------------------------------------
// f32 [R][Cn] -> bf16 [Cn][R] tiled transpose
// ---------------------------------------------------------------------------
__global__ __launch_bounds__(256) void k_transpose_f32_bf16(
    const float* __restrict__ in, __hip_bfloat16* __restrict__ out, int R, int Cn)
{
    __shared__ float tile[32][33];
    const int c0 = blockIdx.x * 32, r0 = blockIdx.y * 32;
    const int tx = threadIdx.x & 31, ty = threadIdx.x >> 5;
#pragma unroll
    for (int i = 0; i < 32; i += 8)
        tile[ty + i][tx] = in[(size_t)(r0 + ty + i) * Cn + c0 + tx];
    __syncthreads();
#pragma unroll
    for (int i = 0; i < 32; i += 8)
        out[(size_t)(c0 + ty + i) * R + r0 + tx] = f2b(tile[tx][ty + i]);
}

#define QSCALE 0.1803368801111f   // 0.125 * log2(e)

// ---------------------------------------------------------------------------
// GEMM1 qkv: 128x128 tile, BK=32, 2-phase dbuf LDS (32 KB -> 3 blocks/CU),
// both-sides swizzle -> 2-way bank conflicts. (unchanged from round 8)
// ---------------------------------------------------------------------------
#define QK_STAGE(buf, kt)                                                       \
    {                                                                           \
        const int k0_ = (kt) << 5;                                              \
        _Pragma("unroll")                                                       \
        for (int i = 0; i < 2; ++i) {                                           \
            const int idx = i * 256 + tid;                                      \
            const int r_ = idx >> 2;                                            \
            const int j_ = idx & 3;                                             \
            const int js_ = j_ ^ ((r_ >> 1) & 3);                               \
            __builtin_amdgcn_global_load_lds(                                   \
                (const __attribute__((address_space(1))) void*)(A + (size_t)(m0 + r_) * K + k0_ + js_ * 8), \
                (__attribute__((address_space(3))) void*)(&As[buf][r_][j_ * 8]), 16, 0, 0); \
        }                                                                       \
        _Pragma("unroll")                                                       \
        for (int i = 0; i < 2; ++i) {                                           \
            const int idx = i * 256 + tid;                                      \
            const int r_ = idx >> 2;                                            \
            const int j_ = idx & 3;                                             \
            const int js_ = j_ ^ ((r_ >> 1) & 3);                               \
            __builtin_amdgcn_global_load_lds(                                   \
                (const __attribute__((address_space(1))) void*)(Bt + (size_t)(n0 + r_) * K + k0_ + js_ * 8), \
                (__attribute__((address_space(3))) void*)(&Bs[buf][r_][j_ * 8]), 16, 0, 0); \
        }                                                                       \
    }

__global__ __launch_bounds__(256, 3) void k_gemm_qkv(
    const __hip_bfloat16* __restrict__ A,
    const __hip_bfloat16* __restrict__ Bt,
    const float* __restrict__ bias,
    int K,
    __hip_bfloat16* __restrict__ Qb,
    __hip_bfloat16* __restrict__ Kb,
    __hip_bfloat16* __restrict__ Vt)
{
    __shared__ __hip_bfloat16 As[2][128][32];
    __shared__ __hip_bfloat16 Bs[2][128][32];

    const int tid = threadIdx.x;
    const int lane = tid & 63;
    const int wid = tid >> 6;
    const int wm = wid >> 1, wn = wid & 1;
    const int m0 = blockIdx.y * 128, n0 = blockIdx.x * 128;
    const int l15 = lane & 15, lg = lane >> 4;
    const int rchunk = (lg ^ ((l15 >> 1) & 3)) * 8;   // swizzled read chunk

    f32x4 acc[4][4] = {};
    const int nt = K >> 5;   // 32

    QK_STAGE(0, 0);
    __syncthreads();
    int cur = 0;
    for (int t = 0; t < nt; ++t) {
        if (t + 1 < nt) QK_STAGE(cur ^ 1, t + 1);
        bf16x8 a[4], bb[4];
#pragma unroll
        for (int m = 0; m < 4; ++m)
            a[m] = *(const bf16x8*)&As[cur][wm * 64 + m * 16 + l15][rchunk];
#pragma unroll
        for (int n = 0; n < 4; ++n)
            bb[n] = *(const bf16x8*)&Bs[cur][wn * 64 + n * 16 + l15][rchunk];
        __builtin_amdgcn_s_setprio(1);
#pragma unroll
        for (int m = 0; m < 4; ++m)
#pragma unroll
            for (int n = 0; n < 4; ++n)
                acc[m][n] = __builtin_amdgcn_mfma_f32_16x16x32_bf16(a[m], bb[n], acc[m][n], 0, 0, 0);
        __builtin_amdgcn_s_setprio(0);
        __syncthreads();
        cur ^= 1;
    }

#pragma unroll
    for (int m = 0; m < 4; ++m) {
        const int row = m0 + wm * 64 + m * 16 + lg * 4;
#pragma unroll
        for (int n = 0; n < 4; ++n) {
            const int col = n0 + wn * 64 + n * 16 + l15;
            const float bv = bias[col];
#pragma unroll
            for (int r = 0; r < 4; ++r) {
                const float val = acc[m][n][r] + bv;
                const int rr = row + r;
                const int sec = col >> 10, cw = col & 1023;
                const int hh = cw >> 6, d = cw & 63;
                const int bq = rr >> 11, tt = rr & 2047;
                const int bh = bq * 16 + hh;
                if (sec == 0)
                    Qb[((size_t)bh * 2048 + tt) * 64 + d] = f2b(val * QSCALE);
                else if (sec == 1)
                    Kb[((size_t)bh * 2048 + tt) * 64 + d] = f2b(val);
                else
                    Vt[((size_t)bh * 64 + d) * 2048 + tt] = f2b(val);
            }
        }
    }
}

// ---------------------------------------------------------------------------
// GEMM out: 128x64 tile, BK=32, dbuf, 512 blocks. (unchanged from round 8)
// ---------------------------------------------------------------------------
#define OUT_STAGE(buf, kt)                                                      \
    {                                                                           \
        const int k0_ = (kt) << 5;                                              \
        _Pragma("unroll")                                                       \
        for (int i = 0; i < 2; ++i) {                                           \
            const int idx = i * 256 + tid;                                      \
            const int r_ = idx >> 2;                                            \
            const int j_ = idx & 3;                                             \
            const int js_ = j_ ^ ((r_ >> 1) & 3);                               \
            __builtin_amdgcn_global_load_lds(                                   \
                (const __attribute__((address_space(1))) void*)(A + (size_t)(m0 + r_) * K + k0_ + js_ * 8), \
                (__attribute__((address_space(3))) void*)(&As[buf][r_][j_ * 8]), 16, 0, 0); \
        }                                                                       \
        {                                                                       \
            const int r_ = tid >> 2;                                            \
            const int j_ = tid & 3;                                             \
            const int js_ = j_ ^ ((r_ >> 1) & 3);                               \
            __builtin_amdgcn_global_load_lds(                                   \
                (const __attribute__((address_space(1))) void*)(Bt + (size_t)(n0 + r_) * K + k0_ + js_ * 8), \
                (__attribute__((address_space(3))) void*)(&Bs[buf][r_][j_ * 8]), 16, 0, 0); \
        }                                                                       \
    }

__global__ __launch_bounds__(256, 4) void k_gemm_out(
    const __hip_bfloat16* __restrict__ A,
    const __hip_bfloat16* __restrict__ Bt,
    const float* __restrict__ bias,
    int K, int Nn,
    float* __restrict__ outf)
{
    __shared__ __hip_bfloat16 As[2][128][32];
    __shared__ __hip_bfloat16 Bs[2][64][32];

    const int tid = threadIdx.x;
    const int lane = tid & 63;
    const int wid = tid >> 6;
    const int wm = wid >> 1, wn = wid & 1;
    const int m0 = blockIdx.y * 128, n0 = blockIdx.x * 64;
    const int l15 = lane & 15, lg = lane >> 4;
    const int rchunk = (lg ^ ((l15 >> 1) & 3)) * 8;

    f32x4 acc[4][2] = {};
    const int nt = K >> 5;

    OUT_STAGE(0, 0);
    __syncthreads();
    int cur = 0;
    for (int t = 0; t < nt; ++t) {
        if (t + 1 < nt) OUT_STAGE(cur ^ 1, t + 1);
        bf16x8 a[4], bb[2];
#pragma unroll
        for (int m = 0; m < 4; ++m)
            a[m] = *(const bf16x8*)&As[cur][wm * 64 + m * 16 + l15][rchunk];
#pragma unroll
        for (int n = 0; n < 2; ++n)
            bb[n] = *(const bf16x8*)&Bs[cur][wn * 32 + n * 16 + l15][rchunk];
        __builtin_amdgcn_s_setprio(1);
#pragma unroll
        for (int m = 0; m < 4; ++m)
#pragma unroll
            for (int n = 0; n < 2; ++n)
                acc[m][n] = __builtin_amdgcn_mfma_f32_16x16x32_bf16(a[m], bb[n], acc[m][n], 0, 0, 0);
        __builtin_amdgcn_s_setprio(0);
        __syncthreads();
        cur ^= 1;
    }

#pragma unroll
    for (int m = 0; m < 4; ++m) {
        const int row = m0 + wm * 64 + m * 16 + lg * 4;
#pragma unroll
        for (int n = 0; n < 2; ++n) {
            const int col = n0 + wn * 32 + n * 16 + l15;
            const float bv = bias[col];
#pragma unroll
            for (int r = 0; r < 4; ++r)
                outf[(size_t)(row + r) * Nn + col] = acc[m][n][r] + bv;
        }
    }
}

// ---------------------------------------------------------------------------
// Causal flash attention v7 — 16 q-rows/wave, 1024 blocks, NO K reg dbuf
// (TLP from 3-4 waves/SIMD hides load latency), launch_bounds(256,3) so the
// allocator never spills. Plain loop (no parity peel needed).
// ---------------------------------------------------------------------------
#define DEFER_THR 4.0f

__global__ __launch_bounds__(256, 3) void k_attn(
    const __hip_bfloat16* __restrict__ Qb,
    const __hip_bfloat16* __restrict__ Kb,
    const __hip_bfloat16* __restrict__ Vt,
    __hip_bfloat16* __restrict__ att)
{
    __shared__ __hip_bfloat16 P_lds[4][16 * 64];
    const int tid = threadIdx.x, lane = tid & 63, wid = tid >> 6;
    const int lid = blockIdx.x;
    const int xcd = lid & 7, j = lid >> 3;       // j 0..127
    const int bh = xcd * 4 + (j & 3);            // 4 heads per XCD
    const int tt = j >> 2;                       // 0..31
    const int tile = (tt < 16) ? (31 - tt) : (tt - 16);   // heavy first
    const int q0 = tile * 64;
    const int qw = q0 + wid * 16;
    const int l15 = lane & 15, lg = lane >> 4;
    const int swz = (l15 & 7) << 3;

    const __hip_bfloat16* Qbase = Qb + (size_t)bh * 2048 * 64;
    const __hip_bfloat16* Kbase = Kb + (size_t)bh * 2048 * 64;
    const __hip_bfloat16* Vbase = Vt + (size_t)bh * 64 * 2048;

    const bf16x8 aq0 = *(const bf16x8*)(Qbase + (size_t)(qw + l15) * 64 + lg * 8);
    const bf16x8 aq1 = *(const bf16x8*)(Qbase + (size_t)(qw + l15) * 64 + 32 + lg * 8);

    f32x4 o[4] = {};
    float mr_ = -1e30f, lr_ = 0.f;

    const int nfull = qw >> 6;
    __hip_bfloat16* Pw = &P_lds[wid][0];

    for (int t = 0; t < nfull; ++t) {
        const int ks = t * 64;
        // QK^T: load K fragments and consume immediately (regs freed after)
        f32x4 s[4] = {};
#pragma unroll
        for (int kf = 0; kf < 4; ++kf) {
            const __hip_bfloat16* kp = Kbase + (size_t)(ks + kf * 16 + l15) * 64 + lg * 8;
            const bf16x8 k0 = *(const bf16x8*)(kp);
            const bf16x8 k1 = *(const bf16x8*)(kp + 32);
            s[kf] = __builtin_amdgcn_mfma_f32_16x16x32_bf16(k0, aq0, s[kf], 0, 0, 0);
            s[kf] = __builtin_amdgcn_mfma_f32_16x16x32_bf16(k1, aq1, s[kf], 0, 0, 0);
        }
        // V prefetch: in flight while softmax runs on the VALU
        bf16x8 bv[4][2];
#pragma unroll
        for (int dc = 0; dc < 4; ++dc) {
            const __hip_bfloat16* vp = Vbase + (size_t)(dc * 16 + l15) * 2048 + ks + lg * 8;
            bv[dc][0] = *(const bf16x8*)(vp);
            bv[dc][1] = *(const bf16x8*)(vp + 32);
        }
        // online softmax, lane-local rows, defer-max
        float px = fmaxf(fmaxf(fmaxf(s[0][0], s[0][1]), fmaxf(s[0][2], s[0][3])),
                         fmaxf(fmaxf(s[1][0], s[1][1]), fmaxf(s[1][2], s[1][3])));
        px = fmaxf(px, fmaxf(fmaxf(fmaxf(s[2][0], s[2][1]), fmaxf(s[2][2], s[2][3])),
                             fmaxf(fmaxf(s[3][0], s[3][1]), fmaxf(s[3][2], s[3][3]))));
        px = fmaxf(px, __shfl_xor(px, 16));
        px = fmaxf(px, __shfl_xor(px, 32));
        if (__any(px > mr_ + DEFER_THR)) {
            const float mn_ = fmaxf(mr_, px);
            const float al_ = exp2fast(mr_ - mn_);
            mr_ = mn_; lr_ *= al_;
#pragma unroll
            for (int dc = 0; dc < 4; ++dc)
#pragma unroll
                for (int r = 0; r < 4; ++r) o[dc][r] *= al_;
        }
        float rs_ = 0.f;
#pragma unroll
        for (int kf = 0; kf < 4; ++kf) {
#pragma unroll
            for (int r = 0; r < 4; ++r) {
                s[kf][r] = exp2fast(s[kf][r] - mr_);
                rs_ += s[kf][r];
            }
            uint2 w_;
            w_.x = pack2(s[kf][0], s[kf][1]);
            w_.y = pack2(s[kf][2], s[kf][3]);
            *(uint2*)&Pw[l15 * 64 + ((kf * 16 + lg * 4) ^ swz)] = w_;
        }
        rs_ += __shfl_xor(rs_, 16);
        rs_ += __shfl_xor(rs_, 32);
        lr_ += rs_;
        // PV
#pragma unroll
        for (int c2 = 0; c2 < 2; ++c2) {
            const bf16x8 pb = *(const bf16x8*)&Pw[l15 * 64 + ((c2 * 32 + lg * 8) ^ swz)];
#pragma unroll
            for (int dc = 0; dc < 4; ++dc)
                o[dc] = __builtin_amdgcn_mfma_f32_16x16x32_bf16(bv[dc][c2], pb, o[dc], 0, 0, 0);
        }
    }

    // ---- diagonal tail: keys [nfull*64, qw+16), causal-masked ----
    {
        const int ks = nfull * 64;
        const int qv = qw + l15;
        f32x4 s[4] = {};
#pragma unroll
        for (int kf = 0; kf < 4; ++kf) {
            if (ks + kf * 16 <= qw + 15) {
                const __hip_bfloat16* kp = Kbase + (size_t)(ks + kf * 16 + l15) * 64 + lg * 8;
                const bf16x8 k0 = *(const bf16x8*)(kp);
                const bf16x8 k1 = *(const bf16x8*)(kp + 32);
                s[kf] = __builtin_amdgcn_mfma_f32_16x16x32_bf16(k0, aq0, s[kf], 0, 0, 0);
                s[kf] = __builtin_amdgcn_mfma_f32_16x16x32_bf16(k1, aq1, s[kf], 0, 0, 0);
            }
        }
        bf16x8 bv[4][2];
#pragma unroll
        for (int dc = 0; dc < 4; ++dc) {
            const __hip_bfloat16* vp = Vbase + (size_t)(dc * 16 + l15) * 2048 + ks + lg * 8;
            bv[dc][0] = *(const bf16x8*)(vp);
            bv[dc][1] = *(const bf16x8*)(vp + 32);
        }
        float p[4][4];
        const int kb = ks + lg * 4;
#pragma unroll
        for (int kf = 0; kf < 4; ++kf)
#pragma unroll
            for (int r = 0; r < 4; ++r)
                p[kf][r] = (kb + kf * 16 + r <= qv) ? s[kf][r] : -1e30f;
        float mx = fmaxf(fmaxf(fmaxf(p[0][0], p[0][1]), fmaxf(p[0][2], p[0][3])),
                         fmaxf(fmaxf(p[1][0], p[1][1]), fmaxf(p[1][2], p[1][3])));
        mx = fmaxf(mx, fmaxf(fmaxf(fmaxf(p[2][0], p[2][1]), fmaxf(p[2][2], p[2][3])),
                             fmaxf(fmaxf(p[3][0], p[3][1]), fmaxf(p[3][2], p[3][3]))));
        mx = fmaxf(mx, __shfl_xor(mx, 16));
        mx = fmaxf(mx, __shfl_xor(mx, 32));
        const float mnew = fmaxf(mr_, mx);
        const float al_ = exp2fast(mr_ - mnew);
        mr_ = mnew;
        float rs_ = 0.f;
#pragma unroll
        for (int kf = 0; kf < 4; ++kf)
#pragma unroll
            for (int r = 0; r < 4; ++r) {
                p[kf][r] = exp2fast(p[kf][r] - mnew);
                rs_ += p[kf][r];
            }
        rs_ += __shfl_xor(rs_, 16);
        rs_ += __shfl_xor(rs_, 32);
        lr_ = lr_ * al_ + rs_;
#pragma unroll
        for (int dc = 0; dc < 4; ++dc)
#pragma unroll
            for (int r = 0; r < 4; ++r) o[dc][r] *= al_;
#pragma unroll
        for (int kf = 0; kf < 4; ++kf) {
            uint2 w_;
            w_.x = pack2(p[kf][0], p[kf][1]);
            w_.y = pack2(p[kf][2], p[kf][3]);
            *(uint2*)&Pw[l15 * 64 + ((kf * 16 + lg * 4) ^ swz)] = w_;
        }
#pragma unroll
        for (int c2 = 0; c2 < 2; ++c2) {
            if (ks + c2 * 32 <= qw + 15) {
                const bf16x8 pb = *(const bf16x8*)&Pw[l15 * 64 + ((c2 * 32 + lg * 8) ^ swz)];
#pragma unroll
                for (int dc = 0; dc < 4; ++dc)
                    o[dc] = __builtin_amdgcn_mfma_f32_16x16x32_bf16(bv[dc][c2], pb, o[dc], 0, 0, 0);
            }
        }
    }

    const int bq = bh >> 4, hh = bh & 15;
    const float inv = 1.0f / lr_;
    const size_t rowb = ((size_t)(bq * 2048 + qw + l15)) * 1024 + hh * 64;
#pragma unroll
    for (int dc = 0; dc < 4; ++dc) {
        bf16x4 st;
#pragma unroll
        for (int r = 0; r < 4; ++r)
            st[r] = (short)__bfloat16_as_ushort(__float2bfloat16(o[dc][r] * inv));
        *(bf16x4*)(att + rowb + dc * 16 + lg * 4) = st;
    }
}

// ---------------------------------------------------------------------------
extern "C" void kernel_launch(void* const* d_in, const int* in_sizes, int n_in,
                              void* d_out, int out_size, void* d_ws, size_t ws_size,
                              hipStream_t stream)
{
    const float* x    = (const float*)d_in[0];   // [2,2048,1024]
    const float* Wqkv = (const float*)d_in[1];   // [1024,3072]
    const float* bqkv = (const float*)d_in[2];   // [3072]
    const float* Wo   = (const float*)d_in[3];   // [1024,1024]
    const float* bo   = (const float*)d_in[4];   // [1024]
    float* out = (float*)d_out;                  // [2,2048,1024]

    char* ws = (char*)d_ws;
    const size_t MB = 1024 * 1024;
    __hip_bfloat16* xb    = (__hip_bfloat16*)(ws);            //  8 MB
    __hip_bfloat16* WqkvT = (__hip_bfloat16*)(ws + 8 * MB);   //  6 MB
    __hip_bfloat16* WoT   = (__hip_bfloat16*)(ws + 14 * MB);  //  2 MB
    __hip_bfloat16* Qb    = (__hip_bfloat16*)(ws + 16 * MB);  //  8 MB
    __hip_bfloat16* Kb    = (__hip_bfloat16*)(ws + 24 * MB);  //  8 MB
    __hip_bfloat16* Vt    = (__hip_bfloat16*)(ws + 32 * MB);  //  8 MB
    __hip_bfloat16* att   = (__hip_bfloat16*)(ws + 40 * MB);  //  8 MB

    k_f32_to_bf16<<<2048, 256, 0, stream>>>(x, xb, 4096 * 1024 / 4);
    k_transpose_f32_bf16<<<dim3(96, 32), 256, 0, stream>>>(Wqkv, WqkvT, 1024, 3072);
    k_transpose_f32_bf16<<<dim3(32, 32), 256, 0, stream>>>(Wo, WoT, 1024, 1024);

    k_gemm_qkv<<<dim3(24, 32), 256, 0, stream>>>(
        xb, WqkvT, bqkv, 1024, Qb, Kb, Vt);

    k_attn<<<1024, 256, 0, stream>>>(Qb, Kb, Vt, att);

    k_gemm_out<<<dim3(16, 32), 256, 0, stream>>>(
        att, WoT, bo, 1024, 1024, out);
}

// Round 10
// 140.154 us; speedup vs baseline: 1.7122x; 1.3908x over previous
//
#include <hip/hip_runtime.h>
#include <hip/hip_bf16.h>

typedef __attribute__((ext_vector_type(8))) short bf16x8;
typedef __attribute__((ext_vector_type(4))) short bf16x4;
typedef __attribute__((ext_vector_type(4))) float f32x4;

static __device__ __forceinline__ __hip_bfloat16 f2b(float f) {
    return __float2bfloat16(f);
}
static __device__ __forceinline__ unsigned pack2(float a, float b) {
    unsigned ua = (unsigned)__bfloat16_as_ushort(__float2bfloat16(a));
    unsigned ub = (unsigned)__bfloat16_as_ushort(__float2bfloat16(b));
    return ua | (ub << 16);
}
static __device__ __forceinline__ float exp2fast(float x) {
    return __builtin_amdgcn_exp2f(x);
}

// ---------------------------------------------------------------------------
// f32 -> bf16 elementwise convert
// ---------------------------------------------------------------------------
__global__ __launch_bounds__(256) void k_f32_to_bf16(
    const float* __restrict__ in, __hip_bfloat16* __restrict__ out, int n4)
{
    int i = blockIdx.x * blockDim.x + threadIdx.x;
    int stride = gridDim.x * blockDim.x;
    for (; i < n4; i += stride) {
        float4 v = reinterpret_cast<const float4*>(in)[i];
        __hip_bfloat16* o = out + 4 * (size_t)i;
        o[0] = f2b(v.x); o[1] = f2b(v.y); o[2] = f2b(v.z); o[3] = f2b(v.w);
    }
}

// ---------------------------------------------------------------------------
// f32 [R][Cn] -> bf16 [Cn][R] tiled transpose
// ---------------------------------------------------------------------------
__global__ __launch_bounds__(256) void k_transpose_f32_bf16(
    const float* __restrict__ in, __hip_bfloat16* __restrict__ out, int R, int Cn)
{
    __shared__ float tile[32][33];
    const int c0 = blockIdx.x * 32, r0 = blockIdx.y * 32;
    const int tx = threadIdx.x & 31, ty = threadIdx.x >> 5;
#pragma unroll
    for (int i = 0; i < 32; i += 8)
        tile[ty + i][tx] = in[(size_t)(r0 + ty + i) * Cn + c0 + tx];
    __syncthreads();
#pragma unroll
    for (int i = 0; i < 32; i += 8)
        out[(size_t)(c0 + ty + i) * R + r0 + tx] = f2b(tile[tx][ty + i]);
}

#define QSCALE 0.1803368801111f   // 0.125 * log2(e)

// ---------------------------------------------------------------------------
// GEMM1 qkv: 128x128 tile, BK=32, 2-phase dbuf LDS (32 KB -> 3 blocks/CU),
// both-sides swizzle -> 2-way bank conflicts. (round-8 version, verified)
// ---------------------------------------------------------------------------
#define QK_STAGE(buf, kt)                                                       \
    {                                                                           \
        const int k0_ = (kt) << 5;                                              \
        _Pragma("unroll")                                                       \
        for (int i = 0; i < 2; ++i) {                                           \
            const int idx = i * 256 + tid;                                      \
            const int r_ = idx >> 2;                                            \
            const int j_ = idx & 3;                                             \
            const int js_ = j_ ^ ((r_ >> 1) & 3);                               \
            __builtin_amdgcn_global_load_lds(                                   \
                (const __attribute__((address_space(1))) void*)(A + (size_t)(m0 + r_) * K + k0_ + js_ * 8), \
                (__attribute__((address_space(3))) void*)(&As[buf][r_][j_ * 8]), 16, 0, 0); \
        }                                                                       \
        _Pragma("unroll")                                                       \
        for (int i = 0; i < 2; ++i) {                                           \
            const int idx = i * 256 + tid;                                      \
            const int r_ = idx >> 2;                                            \
            const int j_ = idx & 3;                                             \
            const int js_ = j_ ^ ((r_ >> 1) & 3);                               \
            __builtin_amdgcn_global_load_lds(                                   \
                (const __attribute__((address_space(1))) void*)(Bt + (size_t)(n0 + r_) * K + k0_ + js_ * 8), \
                (__attribute__((address_space(3))) void*)(&Bs[buf][r_][j_ * 8]), 16, 0, 0); \
        }                                                                       \
    }

__global__ __launch_bounds__(256, 3) void k_gemm_qkv(
    const __hip_bfloat16* __restrict__ A,
    const __hip_bfloat16* __restrict__ Bt,
    const float* __restrict__ bias,
    int K,
    __hip_bfloat16* __restrict__ Qb,
    __hip_bfloat16* __restrict__ Kb,
    __hip_bfloat16* __restrict__ Vt)
{
    __shared__ __hip_bfloat16 As[2][128][32];
    __shared__ __hip_bfloat16 Bs[2][128][32];

    const int tid = threadIdx.x;
    const int lane = tid & 63;
    const int wid = tid >> 6;
    const int wm = wid >> 1, wn = wid & 1;
    const int m0 = blockIdx.y * 128, n0 = blockIdx.x * 128;
    const int l15 = lane & 15, lg = lane >> 4;
    const int rchunk = (lg ^ ((l15 >> 1) & 3)) * 8;   // swizzled read chunk

    f32x4 acc[4][4] = {};
    const int nt = K >> 5;   // 32

    QK_STAGE(0, 0);
    __syncthreads();
    int cur = 0;
    for (int t = 0; t < nt; ++t) {
        if (t + 1 < nt) QK_STAGE(cur ^ 1, t + 1);
        bf16x8 a[4], bb[4];
#pragma unroll
        for (int m = 0; m < 4; ++m)
            a[m] = *(const bf16x8*)&As[cur][wm * 64 + m * 16 + l15][rchunk];
#pragma unroll
        for (int n = 0; n < 4; ++n)
            bb[n] = *(const bf16x8*)&Bs[cur][wn * 64 + n * 16 + l15][rchunk];
        __builtin_amdgcn_s_setprio(1);
#pragma unroll
        for (int m = 0; m < 4; ++m)
#pragma unroll
            for (int n = 0; n < 4; ++n)
                acc[m][n] = __builtin_amdgcn_mfma_f32_16x16x32_bf16(a[m], bb[n], acc[m][n], 0, 0, 0);
        __builtin_amdgcn_s_setprio(0);
        __syncthreads();
        cur ^= 1;
    }

#pragma unroll
    for (int m = 0; m < 4; ++m) {
        const int row = m0 + wm * 64 + m * 16 + lg * 4;
#pragma unroll
        for (int n = 0; n < 4; ++n) {
            const int col = n0 + wn * 64 + n * 16 + l15;
            const float bv = bias[col];
#pragma unroll
            for (int r = 0; r < 4; ++r) {
                const float val = acc[m][n][r] + bv;
                const int rr = row + r;
                const int sec = col >> 10, cw = col & 1023;
                const int hh = cw >> 6, d = cw & 63;
                const int bq = rr >> 11, tt = rr & 2047;
                const int bh = bq * 16 + hh;
                if (sec == 0)
                    Qb[((size_t)bh * 2048 + tt) * 64 + d] = f2b(val * QSCALE);
                else if (sec == 1)
                    Kb[((size_t)bh * 2048 + tt) * 64 + d] = f2b(val);
                else
                    Vt[((size_t)bh * 64 + d) * 2048 + tt] = f2b(val);
            }
        }
    }
}

// ---------------------------------------------------------------------------
// GEMM out: 128x64 tile, BK=32, dbuf, 512 blocks. (round-8 version, verified)
// ---------------------------------------------------------------------------
#define OUT_STAGE(buf, kt)                                                      \
    {                                                                           \
        const int k0_ = (kt) << 5;                                              \
        _Pragma("unroll")                                                       \
        for (int i = 0; i < 2; ++i) {                                           \
            const int idx = i * 256 + tid;                                      \
            const int r_ = idx >> 2;                                            \
            const int j_ = idx & 3;                                             \
            const int js_ = j_ ^ ((r_ >> 1) & 3);                               \
            __builtin_amdgcn_global_load_lds(                                   \
                (const __attribute__((address_space(1))) void*)(A + (size_t)(m0 + r_) * K + k0_ + js_ * 8), \
                (__attribute__((address_space(3))) void*)(&As[buf][r_][j_ * 8]), 16, 0, 0); \
        }                                                                       \
        {                                                                       \
            const int r_ = tid >> 2;                                            \
            const int j_ = tid & 3;                                             \
            const int js_ = j_ ^ ((r_ >> 1) & 3);                               \
            __builtin_amdgcn_global_load_lds(                                   \
                (const __attribute__((address_space(1))) void*)(Bt + (size_t)(n0 + r_) * K + k0_ + js_ * 8), \
                (__attribute__((address_space(3))) void*)(&Bs[buf][r_][j_ * 8]), 16, 0, 0); \
        }                                                                       \
    }

__global__ __launch_bounds__(256, 4) void k_gemm_out(
    const __hip_bfloat16* __restrict__ A,
    const __hip_bfloat16* __restrict__ Bt,
    const float* __restrict__ bias,
    int K, int Nn,
    float* __restrict__ outf)
{
    __shared__ __hip_bfloat16 As[2][128][32];
    __shared__ __hip_bfloat16 Bs[2][64][32];

    const int tid = threadIdx.x;
    const int lane = tid & 63;
    const int wid = tid >> 6;
    const int wm = wid >> 1, wn = wid & 1;
    const int m0 = blockIdx.y * 128, n0 = blockIdx.x * 64;
    const int l15 = lane & 15, lg = lane >> 4;
    const int rchunk = (lg ^ ((l15 >> 1) & 3)) * 8;

    f32x4 acc[4][2] = {};
    const int nt = K >> 5;

    OUT_STAGE(0, 0);
    __syncthreads();
    int cur = 0;
    for (int t = 0; t < nt; ++t) {
        if (t + 1 < nt) OUT_STAGE(cur ^ 1, t + 1);
        bf16x8 a[4], bb[2];
#pragma unroll
        for (int m = 0; m < 4; ++m)
            a[m] = *(const bf16x8*)&As[cur][wm * 64 + m * 16 + l15][rchunk];
#pragma unroll
        for (int n = 0; n < 2; ++n)
            bb[n] = *(const bf16x8*)&Bs[cur][wn * 32 + n * 16 + l15][rchunk];
        __builtin_amdgcn_s_setprio(1);
#pragma unroll
        for (int m = 0; m < 4; ++m)
#pragma unroll
            for (int n = 0; n < 2; ++n)
                acc[m][n] = __builtin_amdgcn_mfma_f32_16x16x32_bf16(a[m], bb[n], acc[m][n], 0, 0, 0);
        __builtin_amdgcn_s_setprio(0);
        __syncthreads();
        cur ^= 1;
    }

#pragma unroll
    for (int m = 0; m < 4; ++m) {
        const int row = m0 + wm * 64 + m * 16 + lg * 4;
#pragma unroll
        for (int n = 0; n < 2; ++n) {
            const int col = n0 + wn * 32 + n * 16 + l15;
            const float bv = bias[col];
#pragma unroll
            for (int r = 0; r < 4; ++r)
                outf[(size_t)(row + r) * Nn + col] = acc[m][n][r] + bv;
        }
    }
}

// ---------------------------------------------------------------------------
// Causal flash attention v5 — 32 q-rows/wave, statically-named K double
// buffer (parity-peeled), exp2 domain, defer-max, setprio. (round-6/7
// version, verified 68.5 us)
// ---------------------------------------------------------------------------
#define DEFER_THR 4.0f

#define K_LOAD(BK, KS)                                                          \
    {                                                                           \
        _Pragma("unroll")                                                       \
        for (int kf = 0; kf < 4; ++kf) {                                        \
            const __hip_bfloat16* kp =                                          \
                Kbase + (size_t)((KS) + kf * 16 + l15) * 64 + lg * 8;           \
            BK[kf][0] = *(const bf16x8*)(kp);                                   \
            BK[kf][1] = *(const bf16x8*)(kp + 32);                              \
        }                                                                       \
    }

#define FULL_STEP(BK, BKN, KS)                                                  \
    {                                                                           \
        const int ks_ = (KS);                                                   \
        bf16x8 bv[4][2];                                                        \
        _Pragma("unroll")                                                       \
        for (int dc = 0; dc < 4; ++dc) {                                        \
            const __hip_bfloat16* vp =                                          \
                Vbase + (size_t)(dc * 16 + l15) * 2048 + ks_ + lg * 8;          \
            bv[dc][0] = *(const bf16x8*)(vp);                                   \
            bv[dc][1] = *(const bf16x8*)(vp + 32);                              \
        }                                                                       \
        K_LOAD(BKN, ks_ + 64);                                                  \
        f32x4 s0[4] = {}, s1[4] = {};                                           \
        __builtin_amdgcn_s_setprio(1);                                          \
        _Pragma("unroll")                                                       \
        for (int kf = 0; kf < 4; ++kf) {                                        \
            s0[kf] = __builtin_amdgcn_mfma_f32_16x16x32_bf16(BK[kf][0], aq[0][0], s0[kf], 0, 0, 0); \
            s0[kf] = __builtin_amdgcn_mfma_f32_16x16x32_bf16(BK[kf][1], aq[0][1], s0[kf], 0, 0, 0); \
            s1[kf] = __builtin_amdgcn_mfma_f32_16x16x32_bf16(BK[kf][0], aq[1][0], s1[kf], 0, 0, 0); \
            s1[kf] = __builtin_amdgcn_mfma_f32_16x16x32_bf16(BK[kf][1], aq[1][1], s1[kf], 0, 0, 0); \
        }                                                                       \
        __builtin_amdgcn_s_setprio(0);                                          \
        float px0 = fmaxf(fmaxf(fmaxf(s0[0][0], s0[0][1]), fmaxf(s0[0][2], s0[0][3])), \
                          fmaxf(fmaxf(s0[1][0], s0[1][1]), fmaxf(s0[1][2], s0[1][3]))); \
        px0 = fmaxf(px0, fmaxf(fmaxf(fmaxf(s0[2][0], s0[2][1]), fmaxf(s0[2][2], s0[2][3])), \
                               fmaxf(fmaxf(s0[3][0], s0[3][1]), fmaxf(s0[3][2], s0[3][3])))); \
        float px1 = fmaxf(fmaxf(fmaxf(s1[0][0], s1[0][1]), fmaxf(s1[0][2], s1[0][3])), \
                          fmaxf(fmaxf(s1[1][0], s1[1][1]), fmaxf(s1[1][2], s1[1][3]))); \
        px1 = fmaxf(px1, fmaxf(fmaxf(fmaxf(s1[2][0], s1[2][1]), fmaxf(s1[2][2], s1[2][3])), \
                               fmaxf(fmaxf(s1[3][0], s1[3][1]), fmaxf(s1[3][2], s1[3][3])))); \
        px0 = fmaxf(px0, __shfl_xor(px0, 16));                                  \
        px0 = fmaxf(px0, __shfl_xor(px0, 32));                                  \
        px1 = fmaxf(px1, __shfl_xor(px1, 16));                                  \
        px1 = fmaxf(px1, __shfl_xor(px1, 32));                                  \
        if (__any((px0 > m0 + DEFER_THR) || (px1 > m1 + DEFER_THR))) {          \
            const float mn0 = fmaxf(m0, px0), mn1 = fmaxf(m1, px1);             \
            const float al0 = exp2fast(m0 - mn0), al1 = exp2fast(m1 - mn1);     \
            m0 = mn0; m1 = mn1;                                                 \
            l0 *= al0; l1 *= al1;                                               \
            _Pragma("unroll")                                                   \
            for (int dc = 0; dc < 4; ++dc)                                      \
                _Pragma("unroll")                                               \
                for (int r = 0; r < 4; ++r) {                                   \
                    o[0][dc][r] *= al0;                                         \
                    o[1][dc][r] *= al1;                                         \
                }                                                               \
        }                                                                       \
        float rs0 = 0.f, rs1 = 0.f;                                             \
        _Pragma("unroll")                                                       \
        for (int kf = 0; kf < 4; ++kf) {                                        \
            _Pragma("unroll")                                                   \
            for (int r = 0; r < 4; ++r) {                                       \
                s0[kf][r] = exp2fast(s0[kf][r] - m0);                           \
                s1[kf][r] = exp2fast(s1[kf][r] - m1);                           \
                rs0 += s0[kf][r];                                               \
                rs1 += s1[kf][r];                                               \
            }                                                                   \
            uint2 w0, w1;                                                       \
            w0.x = pack2(s0[kf][0], s0[kf][1]); w0.y = pack2(s0[kf][2], s0[kf][3]); \
            w1.x = pack2(s1[kf][0], s1[kf][1]); w1.y = pack2(s1[kf][2], s1[kf][3]); \
            const int off = l15 * 64 + ((kf * 16 + lg * 4) ^ swz);              \
            *(uint2*)&Pw0[off] = w0;                                            \
            *(uint2*)&Pw1[off] = w1;                                            \
        }                                                                       \
        rs0 += __shfl_xor(rs0, 16); rs0 += __shfl_xor(rs0, 32);                 \
        rs1 += __shfl_xor(rs1, 16); rs1 += __shfl_xor(rs1, 32);                 \
        l0 += rs0; l1 += rs1;                                                   \
        _Pragma("unroll")                                                       \
        for (int c2 = 0; c2 < 2; ++c2) {                                        \
            const int off = l15 * 64 + ((c2 * 32 + lg * 8) ^ swz);              \
            const bf16x8 pb0 = *(const bf16x8*)&Pw0[off];                       \
            const bf16x8 pb1 = *(const bf16x8*)&Pw1[off];                       \
            __builtin_amdgcn_s_setprio(1);                                      \
            _Pragma("unroll")                                                   \
            for (int dc = 0; dc < 4; ++dc) {                                    \
                o[0][dc] = __builtin_amdgcn_mfma_f32_16x16x32_bf16(bv[dc][c2], pb0, o[0][dc], 0, 0, 0); \
                o[1][dc] = __builtin_amdgcn_mfma_f32_16x16x32_bf16(bv[dc][c2], pb1, o[1][dc], 0, 0, 0); \
            }                                                                   \
            __builtin_amdgcn_s_setprio(0);                                      \
        }                                                                       \
    }

#define TAIL_STEP(BK)                                                           \
    {                                                                           \
        const int ks_ = nfull * 64;                                             \
        bf16x8 bv[4][2];                                                        \
        _Pragma("unroll")                                                       \
        for (int dc = 0; dc < 4; ++dc) {                                        \
            const __hip_bfloat16* vp =                                          \
                Vbase + (size_t)(dc * 16 + l15) * 2048 + ks_ + lg * 8;          \
            bv[dc][0] = *(const bf16x8*)(vp);                                   \
            bv[dc][1] = *(const bf16x8*)(vp + 32);                              \
        }                                                                       \
        float mr[2] = {m0, m1}, lr[2] = {l0, l1};                               \
        _Pragma("unroll")                                                       \
        for (int qf = 0; qf < 2; ++qf) {                                        \
            const int qlo = qw + qf * 16;                                       \
            const int qv = qlo + l15;                                           \
            f32x4 s[4] = {};                                                    \
            _Pragma("unroll")                                                   \
            for (int kf = 0; kf < 4; ++kf) {                                    \
                if (ks_ + kf * 16 <= qlo + 15) {                                \
                    s[kf] = __builtin_amdgcn_mfma_f32_16x16x32_bf16(BK[kf][0], aq[qf][0], s[kf], 0, 0, 0); \
                    s[kf] = __builtin_amdgcn_mfma_f32_16x16x32_bf16(BK[kf][1], aq[qf][1], s[kf], 0, 0, 0); \
                }                                                               \
            }                                                                   \
            float p[4][4];                                                      \
            const int kb = ks_ + lg * 4;                                        \
            _Pragma("unroll")                                                   \
            for (int kf = 0; kf < 4; ++kf)                                      \
                _Pragma("unroll")                                               \
                for (int r = 0; r < 4; ++r)                                     \
                    p[kf][r] = (kb + kf * 16 + r <= qv) ? s[kf][r] : -1e30f;    \
            float mx = fmaxf(fmaxf(fmaxf(p[0][0], p[0][1]), fmaxf(p[0][2], p[0][3])), \
                             fmaxf(fmaxf(p[1][0], p[1][1]), fmaxf(p[1][2], p[1][3]))); \
            mx = fmaxf(mx, fmaxf(fmaxf(fmaxf(p[2][0], p[2][1]), fmaxf(p[2][2], p[2][3])), \
                                 fmaxf(fmaxf(p[3][0], p[3][1]), fmaxf(p[3][2], p[3][3])))); \
            mx = fmaxf(mx, __shfl_xor(mx, 16));                                 \
            mx = fmaxf(mx, __shfl_xor(mx, 32));                                 \
            const float mnew = fmaxf(mr[qf], mx);                               \
            const float al = exp2fast(mr[qf] - mnew);                           \
            mr[qf] = mnew;                                                      \
            float rs = 0.f;                                                     \
            _Pragma("unroll")                                                   \
            for (int kf = 0; kf < 4; ++kf)                                      \
                _Pragma("unroll")                                               \
                for (int r = 0; r < 4; ++r) {                                   \
                    p[kf][r] = exp2fast(p[kf][r] - mnew);                       \
                    rs += p[kf][r];                                             \
                }                                                               \
            rs += __shfl_xor(rs, 16);                                           \
            rs += __shfl_xor(rs, 32);                                           \
            lr[qf] = lr[qf] * al + rs;                                          \
            _Pragma("unroll")                                                   \
            for (int dc = 0; dc < 4; ++dc)                                      \
                _Pragma("unroll")                                               \
                for (int r = 0; r < 4; ++r) o[qf][dc][r] *= al;                 \
            __hip_bfloat16* Pw = (qf == 0) ? Pw0 : Pw1;                         \
            _Pragma("unroll")                                                   \
            for (int kf = 0; kf < 4; ++kf) {                                    \
                uint2 w;                                                        \
                w.x = pack2(p[kf][0], p[kf][1]);                                \
                w.y = pack2(p[kf][2], p[kf][3]);                                \
                *(uint2*)&Pw[l15 * 64 + ((kf * 16 + lg * 4) ^ swz)] = w;        \
            }                                                                   \
            _Pragma("unroll")                                                   \
            for (int c2 = 0; c2 < 2; ++c2) {                                    \
                if (ks_ + c2 * 32 <= qlo + 15) {                                \
                    const bf16x8 pb = *(const bf16x8*)&Pw[l15 * 64 + ((c2 * 32 + lg * 8) ^ swz)]; \
                    _Pragma("unroll")                                           \
                    for (int dc = 0; dc < 4; ++dc)                              \
                        o[qf][dc] = __builtin_amdgcn_mfma_f32_16x16x32_bf16(bv[dc][c2], pb, o[qf][dc], 0, 0, 0); \
                }                                                               \
            }                                                                   \
        }                                                                       \
        l0 = lr[0]; l1 = lr[1];                                                 \
    }

__global__ __launch_bounds__(256, 2) void k_attn(
    const __hip_bfloat16* __restrict__ Qb,
    const __hip_bfloat16* __restrict__ Kb,
    const __hip_bfloat16* __restrict__ Vt,
    __hip_bfloat16* __restrict__ att)
{
    __shared__ __hip_bfloat16 P_lds[4][2][16 * 64];
    const int tid = threadIdx.x, lane = tid & 63, wid = tid >> 6;
    const int lid = blockIdx.x;
    const int xcd = lid & 7, j = lid >> 3;
    const int jj = j >> 2;
    const int tile = (jj < 8) ? (15 - jj) : (jj - 8);   // heavy tiles first
    const int bh = xcd * 4 + (j & 3);
    const int q0 = tile * 128;
    const int qw = q0 + wid * 32;
    const int l15 = lane & 15, lg = lane >> 4;
    const int swz = (l15 & 7) << 3;

    const __hip_bfloat16* Qbase = Qb + (size_t)bh * 2048 * 64;
    const __hip_bfloat16* Kbase = Kb + (size_t)bh * 2048 * 64;
    const __hip_bfloat16* Vbase = Vt + (size_t)bh * 64 * 2048;

    bf16x8 aq[2][2];
#pragma unroll
    for (int qf = 0; qf < 2; ++qf)
#pragma unroll
        for (int c = 0; c < 2; ++c)
            aq[qf][c] = *(const bf16x8*)(Qbase + (size_t)(qw + qf * 16 + l15) * 64 + c * 32 + lg * 8);

    f32x4 o[2][4] = {};
    float m0 = -1e30f, m1 = -1e30f, l0 = 0.f, l1 = 0.f;

    const int nfull = qw >> 6;
    __hip_bfloat16* Pw0 = &P_lds[wid][0][0];
    __hip_bfloat16* Pw1 = &P_lds[wid][1][0];

    bf16x8 bkA[4][2], bkB[4][2];
    K_LOAD(bkA, 0);

    if (nfull & 1) {
        FULL_STEP(bkA, bkB, 0);
        for (int t = 1; t < nfull; t += 2) {
            FULL_STEP(bkB, bkA, t * 64);
            FULL_STEP(bkA, bkB, (t + 1) * 64);
        }
        TAIL_STEP(bkB);
    } else {
        for (int t = 0; t < nfull; t += 2) {
            FULL_STEP(bkA, bkB, t * 64);
            FULL_STEP(bkB, bkA, (t + 1) * 64);
        }
        TAIL_STEP(bkA);
    }

    const int bq = bh >> 4, hh = bh & 15;
    const float inv0 = 1.0f / l0, inv1 = 1.0f / l1;
#pragma unroll
    for (int qf = 0; qf < 2; ++qf) {
        const float inv = (qf == 0) ? inv0 : inv1;
        const size_t rowb = ((size_t)(bq * 2048 + qw + qf * 16 + l15)) * 1024 + hh * 64;
#pragma unroll
        for (int dc = 0; dc < 4; ++dc) {
            bf16x4 st;
#pragma unroll
            for (int r = 0; r < 4; ++r)
                st[r] = (short)__bfloat16_as_ushort(__float2bfloat16(o[qf][dc][r] * inv));
            *(bf16x4*)(att + rowb + dc * 16 + lg * 4) = st;
        }
    }
}

// ---------------------------------------------------------------------------
extern "C" void kernel_launch(void* const* d_in, const int* in_sizes, int n_in,
                              void* d_out, int out_size, void* d_ws, size_t ws_size,
                              hipStream_t stream)
{
    const float* x    = (const float*)d_in[0];   // [2,2048,1024]
    const float* Wqkv = (const float*)d_in[1];   // [1024,3072]
    const float* bqkv = (const float*)d_in[2];   // [3072]
    const float* Wo   = (const float*)d_in[3];   // [1024,1024]
    const float* bo   = (const float*)d_in[4];   // [1024]
    float* out = (float*)d_out;                  // [2,2048,1024]

    char* ws = (char*)d_ws;
    const size_t MB = 1024 * 1024;
    __hip_bfloat16* xb    = (__hip_bfloat16*)(ws);            //  8 MB
    __hip_bfloat16* WqkvT = (__hip_bfloat16*)(ws + 8 * MB);   //  6 MB
    __hip_bfloat16* WoT   = (__hip_bfloat16*)(ws + 14 * MB);  //  2 MB
    __hip_bfloat16* Qb    = (__hip_bfloat16*)(ws + 16 * MB);  //  8 MB
    __hip_bfloat16* Kb    = (__hip_bfloat16*)(ws + 24 * MB);  //  8 MB
    __hip_bfloat16* Vt    = (__hip_bfloat16*)(ws + 32 * MB);  //  8 MB
    __hip_bfloat16* att   = (__hip_bfloat16*)(ws + 40 * MB);  //  8 MB

    k_f32_to_bf16<<<2048, 256, 0, stream>>>(x, xb, 4096 * 1024 / 4);
    k_transpose_f32_bf16<<<dim3(96, 32), 256, 0, stream>>>(Wqkv, WqkvT, 1024, 3072);
    k_transpose_f32_bf16<<<dim3(32, 32), 256, 0, stream>>>(Wo, WoT, 1024, 1024);

    k_gemm_qkv<<<dim3(24, 32), 256, 0, stream>>>(
        xb, WqkvT, bqkv, 1024, Qb, Kb, Vt);

    k_attn<<<512, 256, 0, stream>>>(Qb, Kb, Vt, att);

    k_gemm_out<<<dim3(16, 32), 256, 0, stream>>>(
        att, WoT, bo, 1024, 1024, out);
}